// Round 14
// baseline (575.569 us; speedup 1.0000x reference)
//
#include <hip/hip_runtime.h>
#include <hip/hip_bf16.h>

#define E 4096
#define M 12
#define C 64
#define D 64
#define M0 5
#define XD 64
#define EC 128
#define MAIN (M*C*D)        // 49152
#define EXTRA (M0*C*XD)     // 20480
#define TOTAL (MAIN+EXTRA)  // 69632 = 17*4096
#define NSLICE 17
#define KDIM 8256           // per-slice K = 129*64
#define NKB 43              // uniform k-rows per block (129 = 3*43)

typedef float  f32x4  __attribute__((ext_vector_type(4)));
typedef __bf16 bf16x8 __attribute__((ext_vector_type(8)));
typedef unsigned int u32x4 __attribute__((ext_vector_type(4)));
typedef unsigned int u32x2 __attribute__((ext_vector_type(2)));

typedef const __attribute__((address_space(1))) void gvoid;
typedef __attribute__((address_space(3))) void lvoid;

__device__ __forceinline__ float silu_f(float v) { return v / (1.0f + __expf(-v)); }

__device__ __forceinline__ unsigned short f2bf(float f) {
    unsigned u = __builtin_bit_cast(unsigned, f);
    u += 0x7FFFu + ((u >> 16) & 1u);          // RNE
    return (unsigned short)(u >> 16);
}
__device__ __forceinline__ unsigned pack2(float a, float b) {
    return (unsigned)f2bf(a) | ((unsigned)f2bf(b) << 16);
}
__device__ __forceinline__ float asf(unsigned u) { return __builtin_bit_cast(float, u); }

// ---------- Kernel 1: MLP -> h2^T bf16 [129][E] (row 128 = ones) ----------
__global__ __launch_bounds__(256) void mlp_kernel(
    const float* __restrict__ x_edge, const float* __restrict__ W1,
    const float* __restrict__ b1, const float* __restrict__ W2,
    const float* __restrict__ b2, unsigned short* __restrict__ h2t)
{
    __shared__ float xe[16][128];
    __shared__ float h1s[16][128];
    const int t  = threadIdx.x;
    const int b0 = blockIdx.x * 16;
    const int j  = t & 127;
    const int rh = t >> 7;

    #pragma unroll
    for (int i = 0; i < 8; ++i) {
        int lin = t + i * 256;
        int r = lin >> 7, k = lin & 127;
        xe[r][k] = x_edge[(size_t)(b0 + r) * EC + k];
    }
    __syncthreads();
    {
        float acc[8];
        float bb = b1[j];
        #pragma unroll
        for (int it = 0; it < 8; ++it) acc[it] = bb;
        for (int k = 0; k < 128; ++k) {
            float w = W1[k * EC + j];
            #pragma unroll
            for (int it = 0; it < 8; ++it) acc[it] += xe[rh + it * 2][k] * w;
        }
        #pragma unroll
        for (int it = 0; it < 8; ++it) h1s[rh + it * 2][j] = silu_f(acc[it]);
    }
    __syncthreads();
    {
        float acc[8];
        float bb = b2[j];
        #pragma unroll
        for (int it = 0; it < 8; ++it) acc[it] = bb;
        for (int k = 0; k < 128; ++k) {
            float w = W2[k * EC + j];
            #pragma unroll
            for (int it = 0; it < 8; ++it) acc[it] += h1s[rh + it * 2][k] * w;
        }
        #pragma unroll
        for (int it = 0; it < 8; ++it)
            h2t[(size_t)j * E + (b0 + rh + it * 2)] = f2bf(silu_f(acc[it]));
    }
    if (t < 16) h2t[(size_t)128 * E + b0 + t] = 0x3F80;   // 1.0 bf16
}

// ---------- Kernel 2: W3T[s*64+d][k*64+c] = bf16(W3[k][s*4096+c*64+d]) ----------
__global__ __launch_bounds__(256) void w3t_kernel(
    const float* __restrict__ W3, const float* __restrict__ b3,
    unsigned short* __restrict__ w3t)
{
    const int k = blockIdx.x;   // 0..128
    const int s = blockIdx.y;   // 0..16
    __shared__ float tile[64][68];
    const int t = threadIdx.x;
    const float* src = ((k < 128) ? (W3 + (size_t)k * TOTAL) : b3) + s * 4096;

    const int c  = t >> 2;
    const int dp = (t & 3) * 16;
    #pragma unroll
    for (int i = 0; i < 4; ++i) {
        float4 v = *reinterpret_cast<const float4*>(src + c * 64 + dp + i * 4);
        *reinterpret_cast<float4*>(&tile[c][dp + i * 4]) = v;
    }
    __syncthreads();

    const int d  = t >> 2;
    const int cp = (t & 3) * 16;
    unsigned u[8];
    #pragma unroll
    for (int i = 0; i < 8; ++i)
        u[i] = pack2(tile[cp + 2 * i][d], tile[cp + 2 * i + 1][d]);
    unsigned short* dst = w3t + (size_t)(s * 64 + d) * KDIM + k * 64 + cp;
    *reinterpret_cast<u32x4*>(dst)     = u32x4{u[0], u[1], u[2], u[3]};
    *reinterpret_cast<u32x4*>(dst + 8) = u32x4{u[4], u[5], u[6], u[7]};
}

// ---------- Kernel 3: fused weight-gen + contraction ----------
// 816 blocks = 17 s x 3 kz (nk=43) x 16 bx. 4 waves x 64 b-rows.
// PAIR-GRAIN ring: ring-3 slots each holding 2 k-rows of B (16KB) + their
// h rows (1KB) staged by the same global_load_lds stream (5 loads/thread/pair,
// uniform across waves -> exact counted vmcnt(5)). ONE barrier per 2 k-rows.
// Row 42 tail: B via 2-load STAGE1, h preloaded to regs.
__global__ __launch_bounds__(256, 3) void gemm_kernel(
    const float* __restrict__ x, const unsigned short* __restrict__ h2t,
    const unsigned short* __restrict__ w3t, float* __restrict__ out,
    unsigned short* __restrict__ outp, unsigned short* __restrict__ gatep)
{
    __shared__ __align__(16) unsigned short BsB[3][2][4096];  // 49152 B
    __shared__ __align__(16) unsigned short Bsh[3][2][256];   //  3072 B

    const int t  = threadIdx.x;
    const int w  = t >> 6;
    const int l  = t & 63;
    const int p  = l >> 4;
    const int lr = l & 15;

    // block decode, XCD-chunked (816 = 8*102, bijective)
    const int bid  = blockIdx.x;
    const int slot = (bid & 7) * 102 + (bid >> 3);
    const int grp  = slot >> 4;          // 0..50
    const int bx   = slot & 15;
    const int s    = grp / 3;            // 0..16
    const int kz   = grp % 3;
    const int k0   = kz * NKB;
    const int b0   = bx * 256;
    const int m    = (s < 12) ? s : (s - 12);

    // A fragments: x rows for this wave, bf16-packed, resident all kernel
    u32x4 xa[4][2];
    #pragma unroll
    for (int rf = 0; rf < 4; ++rf)
        #pragma unroll
        for (int s2 = 0; s2 < 2; ++s2) {
            const float* xp = x + (size_t)(b0 + w * 64 + rf * 16 + lr) * (M * C)
                              + m * 64 + s2 * 32 + p * 8;
            float4 a = *reinterpret_cast<const float4*>(xp);
            float4 b = *reinterpret_cast<const float4*>(xp + 4);
            xa[rf][s2] = u32x4{pack2(a.x, a.y), pack2(a.z, a.w),
                               pack2(b.x, b.y), pack2(b.z, b.w)};
        }

    // h for tail row 42, preloaded to regs (retires before first counted wait)
    u32x2 h42[4];
    #pragma unroll
    for (int rf = 0; rf < 4; ++rf)
        h42[rf] = *reinterpret_cast<const u32x2*>(
            h2t + (size_t)(k0 + 42) * E + b0 + w * 64 + rf * 16 + p * 4);

    // B staging srcs (wave w stages subtile cf=w): lane l -> (d=w*16+lr, ch=q*4+p)
    const unsigned short* gsrc[2];
    #pragma unroll
    for (int q = 0; q < 2; ++q)
        gsrc[q] = w3t + (size_t)(s * 64 + w * 16 + lr) * KDIM
                  + (size_t)k0 * 64 + (q * 4 + p) * 8;

    // h staging src: wave w covers byte-quarter w of the pair's 1KB h block:
    // row (w>>1), ushort cols (w&1)*128 + l*2  (256B contiguous per wave)
    const unsigned short* hsrc = h2t + (size_t)(k0 + (w >> 1)) * E + b0
                                 + (w & 1) * 128 + l * 2;

// STAGE2: 4 B-loads (16B) + 1 h-load (4B) per thread — 5 counted VMEM ops.
#define STAGE2(buf, pr)                                                         \
    {                                                                           \
        _Pragma("unroll")                                                       \
        for (int rr = 0; rr < 2; ++rr)                                          \
            _Pragma("unroll")                                                   \
            for (int q = 0; q < 2; ++q)                                         \
                __builtin_amdgcn_global_load_lds(                               \
                    (gvoid*)(gsrc[q] + (size_t)(2 * (pr) + rr) * 64),           \
                    (lvoid*)(&BsB[buf][rr][(w * 2 + q) * 512]), 16, 0, 0);      \
        __builtin_amdgcn_global_load_lds(                                       \
            (gvoid*)(hsrc + (size_t)(2 * (pr)) * E),                            \
            (lvoid*)((char*)&Bsh[buf][0][0] + w * 256), 4, 0, 0);               \
    }
// STAGE1: row 42's B only (2 loads)
#define STAGE1(buf)                                                             \
    {                                                                           \
        _Pragma("unroll")                                                       \
        for (int q = 0; q < 2; ++q)                                             \
            __builtin_amdgcn_global_load_lds(                                   \
                (gvoid*)(gsrc[q] + (size_t)42 * 64),                            \
                (lvoid*)(&BsB[buf][0][(w * 2 + q) * 512]), 16, 0, 0);           \
    }

    f32x4 acc[4][4];
    #pragma unroll
    for (int a = 0; a < 4; ++a)
        #pragma unroll
        for (int b = 0; b < 4; ++b) acc[a][b] = f32x4{0.f, 0.f, 0.f, 0.f};
    const f32x4 zf = {0.f, 0.f, 0.f, 0.f};

// KBODY: proven form — h (from slot's h region) on C-side, tt transient.
#define KBODY(curv, rr)                                                         \
    {                                                                           \
        float h[4][4];                                                          \
        _Pragma("unroll")                                                       \
        for (int rf = 0; rf < 4; ++rf) {                                        \
            u32x2 hv = *reinterpret_cast<const u32x2*>(                         \
                &Bsh[curv][rr][w * 64 + rf * 16 + p * 4]);                      \
            h[rf][0] = asf(hv.x << 16);                                         \
            h[rf][1] = asf(hv.x & 0xFFFF0000u);                                 \
            h[rf][2] = asf(hv.y << 16);                                         \
            h[rf][3] = asf(hv.y & 0xFFFF0000u);                                 \
        }                                                                       \
        __builtin_amdgcn_s_setprio(1);                                          \
        _Pragma("unroll")                                                       \
        for (int cf = 0; cf < 4; ++cf) {                                        \
            u32x4 B0 = *reinterpret_cast<const u32x4*>(                         \
                &BsB[curv][rr][(cf * 2 + 0) * 512 + l * 8]);                    \
            u32x4 B1 = *reinterpret_cast<const u32x4*>(                         \
                &BsB[curv][rr][(cf * 2 + 1) * 512 + l * 8]);                    \
            _Pragma("unroll")                                                   \
            for (int rf = 0; rf < 4; ++rf) {                                    \
                f32x4 tt = __builtin_amdgcn_mfma_f32_16x16x32_bf16(             \
                    __builtin_bit_cast(bf16x8, xa[rf][0]),                      \
                    __builtin_bit_cast(bf16x8, B0), zf, 0, 0, 0);               \
                tt = __builtin_amdgcn_mfma_f32_16x16x32_bf16(                   \
                    __builtin_bit_cast(bf16x8, xa[rf][1]),                      \
                    __builtin_bit_cast(bf16x8, B1), tt, 0, 0, 0);               \
                acc[rf][cf][0] += h[rf][0] * tt[0];                             \
                acc[rf][cf][1] += h[rf][1] * tt[1];                             \
                acc[rf][cf][2] += h[rf][2] * tt[2];                             \
                acc[rf][cf][3] += h[rf][3] * tt[3];                             \
            }                                                                   \
        }                                                                       \
        __builtin_amdgcn_s_setprio(0);                                          \
    }
// KBODY42: h from regs, B from slot 0 row 0
#define KBODY42()                                                               \
    {                                                                           \
        float h[4][4];                                                          \
        _Pragma("unroll")                                                       \
        for (int rf = 0; rf < 4; ++rf) {                                        \
            h[rf][0] = asf(h42[rf].x << 16);                                    \
            h[rf][1] = asf(h42[rf].x & 0xFFFF0000u);                            \
            h[rf][2] = asf(h42[rf].y << 16);                                    \
            h[rf][3] = asf(h42[rf].y & 0xFFFF0000u);                            \
        }                                                                       \
        __builtin_amdgcn_s_setprio(1);                                          \
        _Pragma("unroll")                                                       \
        for (int cf = 0; cf < 4; ++cf) {                                        \
            u32x4 B0 = *reinterpret_cast<const u32x4*>(                         \
                &BsB[0][0][(cf * 2 + 0) * 512 + l * 8]);                        \
            u32x4 B1 = *reinterpret_cast<const u32x4*>(                         \
                &BsB[0][0][(cf * 2 + 1) * 512 + l * 8]);                        \
            _Pragma("unroll")                                                   \
            for (int rf = 0; rf < 4; ++rf) {                                    \
                f32x4 tt = __builtin_amdgcn_mfma_f32_16x16x32_bf16(             \
                    __builtin_bit_cast(bf16x8, xa[rf][0]),                      \
                    __builtin_bit_cast(bf16x8, B0), zf, 0, 0, 0);               \
                tt = __builtin_amdgcn_mfma_f32_16x16x32_bf16(                   \
                    __builtin_bit_cast(bf16x8, xa[rf][1]),                      \
                    __builtin_bit_cast(bf16x8, B1), tt, 0, 0, 0);               \
                acc[rf][cf][0] += h[rf][0] * tt[0];                             \
                acc[rf][cf][1] += h[rf][1] * tt[1];                             \
                acc[rf][cf][2] += h[rf][2] * tt[2];                             \
                acc[rf][cf][3] += h[rf][3] * tt[3];                             \
            }                                                                   \
        }                                                                       \
        __builtin_amdgcn_s_setprio(0);                                          \
    }

    STAGE2(0, 0);               // pairs 0,1 in flight (10 counted loads)
    STAGE2(1, 1);

    int cur = 0;                // slot holding pair pr's data
    #pragma unroll 1
    for (int pr = 0; pr < 19; ++pr) {           // pairs 0..18
        // pair pr's 5 loads landed (pr+1's 5 still out); own prev reads retired.
        asm volatile("s_waitcnt vmcnt(5) lgkmcnt(0)" ::: "memory");
        __builtin_amdgcn_s_barrier();
        int nxt = (cur == 0) ? 2 : cur - 1;     // slot (pr+2)%3 == (pr-1)%3
        STAGE2(nxt, pr + 2);
        KBODY(cur, 0);
        KBODY(cur, 1);
        cur = (cur == 2) ? 0 : cur + 1;
    }
    // pair 19 (slot 1): stage tail row 42 into slot 0 (freed after pair 18)
    asm volatile("s_waitcnt vmcnt(5) lgkmcnt(0)" ::: "memory");
    __builtin_amdgcn_s_barrier();
    STAGE1(0);
    KBODY(1, 0);
    KBODY(1, 1);
    // pair 20 (slot 2): outstanding = pair20(5) + tail(2) -> wait 2
    asm volatile("s_waitcnt vmcnt(2) lgkmcnt(0)" ::: "memory");
    __builtin_amdgcn_s_barrier();
    KBODY(2, 0);
    KBODY(2, 1);
    // row 42 (slot 0, row 0)
    asm volatile("s_waitcnt vmcnt(0) lgkmcnt(0)" ::: "memory");
    __builtin_amdgcn_s_barrier();
    KBODY42();
#undef STAGE2
#undef STAGE1
#undef KBODY
#undef KBODY42

    // epilogue: partial stores (no atomics)
    if (s < 12) {
        if (kz == 0) {
            #pragma unroll
            for (int rf = 0; rf < 4; ++rf)
                #pragma unroll
                for (int cf = 0; cf < 4; ++cf)
                    #pragma unroll
                    for (int r = 0; r < 4; ++r) {
                        int b = b0 + w * 64 + rf * 16 + p * 4 + r;
                        int d = cf * 16 + lr;
                        out[(size_t)b * (M * D) + s * D + d] = acc[rf][cf][r];
                    }
        } else {
            unsigned short* ob = outp + (size_t)(kz - 1) * (E * M * D);
            #pragma unroll
            for (int rf = 0; rf < 4; ++rf)
                #pragma unroll
                for (int cf = 0; cf < 4; ++cf)
                    #pragma unroll
                    for (int r = 0; r < 4; ++r) {
                        int b = b0 + w * 64 + rf * 16 + p * 4 + r;
                        int d = cf * 16 + lr;
                        ob[(size_t)b * (M * D) + s * D + d] = f2bf(acc[rf][cf][r]);
                    }
        }
    } else {
        unsigned short* gp = gatep + (size_t)((s - 12) * 3 + kz) * (E * 64);
        #pragma unroll
        for (int rf = 0; rf < 4; ++rf)
            #pragma unroll
            for (int cf = 0; cf < 4; ++cf)
                #pragma unroll
                for (int r = 0; r < 4; ++r) {
                    int b = b0 + w * 64 + rf * 16 + p * 4 + r;
                    int d = cf * 16 + lr;
                    gp[(size_t)b * 64 + d] = f2bf(acc[rf][cf][r]);
                }
    }
}

// ---------- Kernel 4: out += 2 bf16 main partials; gate = sum of 15 bf16 partials ----------
__global__ __launch_bounds__(256) void reduce_kernel(
    float* __restrict__ out, const unsigned short* __restrict__ outp,
    const unsigned short* __restrict__ gatep)
{
    const int MAIN4 = E * M * D / 4;     // 786432
    int i = blockIdx.x * 256 + threadIdx.x;
    if (i < MAIN4) {
        float4 a = reinterpret_cast<float4*>(out)[i];
        u32x2 p0 = *reinterpret_cast<const u32x2*>(outp + (size_t)i * 4);
        u32x2 p1 = *reinterpret_cast<const u32x2*>(outp + (size_t)E * M * D + (size_t)i * 4);
        a.x += asf(p0.x << 16)         + asf(p1.x << 16);
        a.y += asf(p0.x & 0xFFFF0000u) + asf(p1.x & 0xFFFF0000u);
        a.z += asf(p0.y << 16)         + asf(p1.y << 16);
        a.w += asf(p0.y & 0xFFFF0000u) + asf(p1.y & 0xFFFF0000u);
        reinterpret_cast<float4*>(out)[i] = a;
    } else {
        int j = i - MAIN4;               // < 65536
        float4 sum = make_float4(0.f, 0.f, 0.f, 0.f);
        #pragma unroll
        for (int q = 0; q < 15; ++q) {
            u32x2 v = *reinterpret_cast<const u32x2*>(
                gatep + (size_t)q * (E * 64) + (size_t)j * 4);
            sum.x += asf(v.x << 16);
            sum.y += asf(v.x & 0xFFFF0000u);
            sum.z += asf(v.y << 16);
            sum.w += asf(v.y & 0xFFFF0000u);
        }
        reinterpret_cast<float4*>(out + (size_t)E * M * D)[j] = sum;
    }
}

extern "C" void kernel_launch(void* const* d_in, const int* in_sizes, int n_in,
                              void* d_out, int out_size, void* d_ws, size_t ws_size,
                              hipStream_t stream)
{
    const float* x      = (const float*)d_in[0];
    const float* x_edge = (const float*)d_in[1];
    const float* W1     = (const float*)d_in[2];
    const float* b1     = (const float*)d_in[3];
    const float* W2     = (const float*)d_in[4];
    const float* b2     = (const float*)d_in[5];
    const float* W3     = (const float*)d_in[6];
    const float* b3     = (const float*)d_in[7];

    float* out = (float*)d_out;

    // ws: W3T 17,965,056 | h2t 1,056,768 | outp bf16 x2 12,582,912 | gatep bf16 x15 7,864,320
    char* ws = (char*)d_ws;
    unsigned short* w3t   = (unsigned short*)ws;
    unsigned short* h2t   = (unsigned short*)(ws + 17965056);
    unsigned short* outp  = (unsigned short*)(ws + 19021824);
    unsigned short* gatep = (unsigned short*)(ws + 31604736);

    mlp_kernel<<<E / 16, 256, 0, stream>>>(x_edge, W1, b1, W2, b2, h2t);
    w3t_kernel<<<dim3(129, NSLICE), 256, 0, stream>>>(W3, b3, w3t);
    gemm_kernel<<<816, 256, 0, stream>>>(x, h2t, w3t, out, outp, gatep);
    reduce_kernel<<<3328, 256, 0, stream>>>(out, outp, gatep);
}

// Round 15
// 138.096 us; speedup vs baseline: 4.1679x; 4.1679x over previous
//
#include <hip/hip_runtime.h>
#include <hip/hip_bf16.h>

#define E 4096
#define M 12
#define C 64
#define D 64
#define M0 5
#define XD 64
#define EC 128
#define MAIN (M*C*D)        // 49152
#define EXTRA (M0*C*XD)     // 20480
#define TOTAL (MAIN+EXTRA)  // 69632 = 17*4096
#define NSLICE 17
#define KDIM 8256           // per-slice K = 129*64
#define NKB 43              // uniform k-rows per block (129 = 3*43)

typedef float  f32x4  __attribute__((ext_vector_type(4)));
typedef __bf16 bf16x8 __attribute__((ext_vector_type(8)));
typedef unsigned int u32x4 __attribute__((ext_vector_type(4)));
typedef unsigned int u32x2 __attribute__((ext_vector_type(2)));

typedef const __attribute__((address_space(1))) void gvoid;
typedef __attribute__((address_space(3))) void lvoid;

__device__ __forceinline__ float silu_f(float v) { return v / (1.0f + __expf(-v)); }

__device__ __forceinline__ unsigned short f2bf(float f) {
    unsigned u = __builtin_bit_cast(unsigned, f);
    u += 0x7FFFu + ((u >> 16) & 1u);          // RNE
    return (unsigned short)(u >> 16);
}
__device__ __forceinline__ unsigned pack2(float a, float b) {
    return (unsigned)f2bf(a) | ((unsigned)f2bf(b) << 16);
}
__device__ __forceinline__ float asf(unsigned u) { return __builtin_bit_cast(float, u); }

// ---------- Kernel 1: MLP -> h2^T bf16 [129][E] (row 128 = ones) ----------
__global__ __launch_bounds__(256) void mlp_kernel(
    const float* __restrict__ x_edge, const float* __restrict__ W1,
    const float* __restrict__ b1, const float* __restrict__ W2,
    const float* __restrict__ b2, unsigned short* __restrict__ h2t)
{
    __shared__ float xe[16][128];
    __shared__ float h1s[16][128];
    const int t  = threadIdx.x;
    const int b0 = blockIdx.x * 16;
    const int j  = t & 127;
    const int rh = t >> 7;

    #pragma unroll
    for (int i = 0; i < 8; ++i) {
        int lin = t + i * 256;
        int r = lin >> 7, k = lin & 127;
        xe[r][k] = x_edge[(size_t)(b0 + r) * EC + k];
    }
    __syncthreads();
    {
        float acc[8];
        float bb = b1[j];
        #pragma unroll
        for (int it = 0; it < 8; ++it) acc[it] = bb;
        for (int k = 0; k < 128; ++k) {
            float w = W1[k * EC + j];
            #pragma unroll
            for (int it = 0; it < 8; ++it) acc[it] += xe[rh + it * 2][k] * w;
        }
        #pragma unroll
        for (int it = 0; it < 8; ++it) h1s[rh + it * 2][j] = silu_f(acc[it]);
    }
    __syncthreads();
    {
        float acc[8];
        float bb = b2[j];
        #pragma unroll
        for (int it = 0; it < 8; ++it) acc[it] = bb;
        for (int k = 0; k < 128; ++k) {
            float w = W2[k * EC + j];
            #pragma unroll
            for (int it = 0; it < 8; ++it) acc[it] += h1s[rh + it * 2][k] * w;
        }
        #pragma unroll
        for (int it = 0; it < 8; ++it)
            h2t[(size_t)j * E + (b0 + rh + it * 2)] = f2bf(silu_f(acc[it]));
    }
    if (t < 16) h2t[(size_t)128 * E + b0 + t] = 0x3F80;   // 1.0 bf16
}

// ---------- Kernel 2: W3T[s*64+d][k*64+c] = bf16(W3[k][s*4096+c*64+d]) ----------
__global__ __launch_bounds__(256) void w3t_kernel(
    const float* __restrict__ W3, const float* __restrict__ b3,
    unsigned short* __restrict__ w3t)
{
    const int k = blockIdx.x;   // 0..128
    const int s = blockIdx.y;   // 0..16
    __shared__ float tile[64][68];
    const int t = threadIdx.x;
    const float* src = ((k < 128) ? (W3 + (size_t)k * TOTAL) : b3) + s * 4096;

    const int c  = t >> 2;
    const int dp = (t & 3) * 16;
    #pragma unroll
    for (int i = 0; i < 4; ++i) {
        float4 v = *reinterpret_cast<const float4*>(src + c * 64 + dp + i * 4);
        *reinterpret_cast<float4*>(&tile[c][dp + i * 4]) = v;
    }
    __syncthreads();

    const int d  = t >> 2;
    const int cp = (t & 3) * 16;
    unsigned u[8];
    #pragma unroll
    for (int i = 0; i < 8; ++i)
        u[i] = pack2(tile[cp + 2 * i][d], tile[cp + 2 * i + 1][d]);
    unsigned short* dst = w3t + (size_t)(s * 64 + d) * KDIM + k * 64 + cp;
    *reinterpret_cast<u32x4*>(dst)     = u32x4{u[0], u[1], u[2], u[3]};
    *reinterpret_cast<u32x4*>(dst + 8) = u32x4{u[4], u[5], u[6], u[7]};
}

// ---------- Kernel 3: fused weight-gen + contraction ----------
// R10's ring-3 one-barrier skeleton, KBODY pure MFMA:
// axs = bf16(h * x) built per k-row on VALU (no B / MFMA-output dependency),
// acc accumulated natively in the MFMA C operand (AGPR-only).
// launch_bounds(256,2): 256-reg budget -> no spill. Best measured: 111 us.
__global__ __launch_bounds__(256, 2) void gemm_kernel(
    const float* __restrict__ x, const unsigned short* __restrict__ h2t,
    const unsigned short* __restrict__ w3t, float* __restrict__ out,
    unsigned short* __restrict__ outp, unsigned short* __restrict__ gatep)
{
    __shared__ __align__(16) unsigned short h2s[NKB * 256];   // 22016 B
    __shared__ __align__(16) unsigned short Bs[3][4096];      // 3 x 8 KB ring

    const int t  = threadIdx.x;
    const int w  = t >> 6;
    const int l  = t & 63;
    const int p  = l >> 4;
    const int lr = l & 15;

    // block decode, XCD-chunked (816 = 8*102, bijective)
    const int bid  = blockIdx.x;
    const int slot = (bid & 7) * 102 + (bid >> 3);
    const int grp  = slot >> 4;          // 0..50
    const int bx   = slot & 15;
    const int s    = grp / 3;            // 0..16
    const int kz   = grp % 3;
    const int k0   = kz * NKB;
    const int b0   = bx * 256;
    const int m    = (s < 12) ? s : (s - 12);

    // stage h2^T tile [43][256 cols] (512 B per row)
    {
        const char* h2g = (const char*)(h2t + (size_t)k0 * E + b0);
        for (int lin = t * 16; lin < NKB * 512; lin += 4096) {
            int kl = lin >> 9, off = lin & 511;
            *reinterpret_cast<u32x4*>((char*)h2s + lin) =
                *reinterpret_cast<const u32x4*>(h2g + (size_t)kl * (E * 2) + off);
        }
    }

    // A fragments: x rows for this wave, bf16-packed, resident all kernel
    u32x4 xa[4][2];
    #pragma unroll
    for (int rf = 0; rf < 4; ++rf)
        #pragma unroll
        for (int s2 = 0; s2 < 2; ++s2) {
            const float* xp = x + (size_t)(b0 + w * 64 + rf * 16 + lr) * (M * C)
                              + m * 64 + s2 * 32 + p * 8;
            float4 a = *reinterpret_cast<const float4*>(xp);
            float4 b = *reinterpret_cast<const float4*>(xp + 4);
            xa[rf][s2] = u32x4{pack2(a.x, a.y), pack2(a.z, a.w),
                               pack2(b.x, b.y), pack2(b.z, b.w)};
        }

    // staging source (wave w stages subtile cf=w): lane l -> (d=w*16+lr, ch=q*4+p)
    const unsigned short* gsrc[2];
    #pragma unroll
    for (int q = 0; q < 2; ++q)
        gsrc[q] = w3t + (size_t)(s * 64 + w * 16 + lr) * KDIM
                  + (size_t)k0 * 64 + (q * 4 + p) * 8;

#define STAGE(buf, kr)                                                          \
    {                                                                           \
        _Pragma("unroll")                                                       \
        for (int q = 0; q < 2; ++q)                                             \
            __builtin_amdgcn_global_load_lds(                                   \
                (gvoid*)(gsrc[q] + (size_t)(kr) * 64),                          \
                (lvoid*)(&Bs[buf][(w * 2 + q) * 512]), 16, 0, 0);               \
    }

    f32x4 acc[4][4];
    #pragma unroll
    for (int a = 0; a < 4; ++a)
        #pragma unroll
        for (int b = 0; b < 4; ++b) acc[a][b] = f32x4{0.f, 0.f, 0.f, 0.f};

    u32x4 axs[4][2];   // h-scaled A fragments for the current k-row

// ASCALE: axs = bf16(h[b,kr] * x[b,c]) — pure VGPR VALU; lane's b-row = lr.
#define ASCALE(kr)                                                              \
    {                                                                           \
        _Pragma("unroll")                                                       \
        for (int rf = 0; rf < 4; ++rf) {                                        \
            unsigned hu = (unsigned)h2s[(kr) * 256 + w * 64 + rf * 16 + lr];    \
            float hf = asf(hu << 16);                                           \
            _Pragma("unroll")                                                   \
            for (int s2 = 0; s2 < 2; ++s2)                                      \
                _Pragma("unroll")                                               \
                for (int i = 0; i < 4; ++i) {                                   \
                    unsigned u = xa[rf][s2][i];                                 \
                    float lo = asf(u << 16) * hf;                               \
                    float hi = asf(u & 0xFFFF0000u) * hf;                       \
                    unsigned r;                                                 \
                    asm("v_cvt_pk_bf16_f32 %0, %1, %2"                          \
                        : "=v"(r) : "v"(lo), "v"(hi));                          \
                    axs[rf][s2][i] = r;                                         \
                }                                                               \
        }                                                                       \
    }

// KBODY: pure MFMA cluster, accumulating natively into acc (AGPR-only).
#define KBODY(curv)                                                             \
    {                                                                           \
        __builtin_amdgcn_s_setprio(1);                                          \
        _Pragma("unroll")                                                       \
        for (int cf = 0; cf < 4; ++cf) {                                        \
            u32x4 B0 = *reinterpret_cast<const u32x4*>(                         \
                &Bs[curv][(cf * 2 + 0) * 512 + l * 8]);                         \
            u32x4 B1 = *reinterpret_cast<const u32x4*>(                         \
                &Bs[curv][(cf * 2 + 1) * 512 + l * 8]);                         \
            _Pragma("unroll")                                                   \
            for (int rf = 0; rf < 4; ++rf) {                                    \
                acc[rf][cf] = __builtin_amdgcn_mfma_f32_16x16x32_bf16(          \
                    __builtin_bit_cast(bf16x8, axs[rf][0]),                     \
                    __builtin_bit_cast(bf16x8, B0), acc[rf][cf], 0, 0, 0);      \
                acc[rf][cf] = __builtin_amdgcn_mfma_f32_16x16x32_bf16(          \
                    __builtin_bit_cast(bf16x8, axs[rf][1]),                     \
                    __builtin_bit_cast(bf16x8, B1), acc[rf][cf], 0, 0, 0);      \
            }                                                                   \
        }                                                                       \
        __builtin_amdgcn_s_setprio(0);                                          \
    }

    __syncthreads();            // h2s visible; everything drained

    STAGE(0, 0);                // ring prologue: slots 0,1 in flight
    STAGE(1, 1);

    int cur = 0;                // slot holding kr's data
    #pragma unroll 1
    for (int kr = 0; kr < NKB - 2; ++kr) {      // kr = 0..40
        // own kr-loads landed (4 outstanding -> wait 2); own kr-1 LDS reads
        // retired (lgkm 0); barrier globalizes both facts.
        asm volatile("s_waitcnt vmcnt(2) lgkmcnt(0)" ::: "memory");
        __builtin_amdgcn_s_barrier();
        int nxt = (cur == 0) ? 2 : cur - 1;     // slot (kr+2)%3 == (kr-1)%3
        STAGE(nxt, kr + 2);                     // stage ASAP: ~2 iters lead time
        ASCALE(kr);                             // VALU; overlaps others' MFMA
        KBODY(cur);                             // pure MFMA burst
        cur = (cur == 2) ? 0 : cur + 1;
    }
    // kr = 41: 42's loads may be outstanding (2)
    asm volatile("s_waitcnt vmcnt(2) lgkmcnt(0)" ::: "memory");
    __builtin_amdgcn_s_barrier();
    ASCALE(NKB - 2);
    KBODY(cur);
    cur = (cur == 2) ? 0 : cur + 1;
    // kr = 42: drain
    asm volatile("s_waitcnt vmcnt(0) lgkmcnt(0)" ::: "memory");
    __builtin_amdgcn_s_barrier();
    ASCALE(NKB - 1);
    KBODY(cur);
#undef STAGE
#undef ASCALE
#undef KBODY

    // epilogue: partial stores (no atomics)
    if (s < 12) {
        if (kz == 0) {
            #pragma unroll
            for (int rf = 0; rf < 4; ++rf)
                #pragma unroll
                for (int cf = 0; cf < 4; ++cf)
                    #pragma unroll
                    for (int r = 0; r < 4; ++r) {
                        int b = b0 + w * 64 + rf * 16 + p * 4 + r;
                        int d = cf * 16 + lr;
                        out[(size_t)b * (M * D) + s * D + d] = acc[rf][cf][r];
                    }
        } else {
            unsigned short* ob = outp + (size_t)(kz - 1) * (E * M * D);
            #pragma unroll
            for (int rf = 0; rf < 4; ++rf)
                #pragma unroll
                for (int cf = 0; cf < 4; ++cf)
                    #pragma unroll
                    for (int r = 0; r < 4; ++r) {
                        int b = b0 + w * 64 + rf * 16 + p * 4 + r;
                        int d = cf * 16 + lr;
                        ob[(size_t)b * (M * D) + s * D + d] = f2bf(acc[rf][cf][r]);
                    }
        }
    } else {
        unsigned short* gp = gatep + (size_t)((s - 12) * 3 + kz) * (E * 64);
        #pragma unroll
        for (int rf = 0; rf < 4; ++rf)
            #pragma unroll
            for (int cf = 0; cf < 4; ++cf)
                #pragma unroll
                for (int r = 0; r < 4; ++r) {
                    int b = b0 + w * 64 + rf * 16 + p * 4 + r;
                    int d = cf * 16 + lr;
                    gp[(size_t)b * 64 + d] = f2bf(acc[rf][cf][r]);
                }
    }
}

// ---------- Kernel 4: out += 2 bf16 main partials; gate = sum of 15 bf16 partials ----------
__global__ __launch_bounds__(256) void reduce_kernel(
    float* __restrict__ out, const unsigned short* __restrict__ outp,
    const unsigned short* __restrict__ gatep)
{
    const int MAIN4 = E * M * D / 4;     // 786432
    int i = blockIdx.x * 256 + threadIdx.x;
    if (i < MAIN4) {
        float4 a = reinterpret_cast<float4*>(out)[i];
        u32x2 p0 = *reinterpret_cast<const u32x2*>(outp + (size_t)i * 4);
        u32x2 p1 = *reinterpret_cast<const u32x2*>(outp + (size_t)E * M * D + (size_t)i * 4);
        a.x += asf(p0.x << 16)         + asf(p1.x << 16);
        a.y += asf(p0.x & 0xFFFF0000u) + asf(p1.x & 0xFFFF0000u);
        a.z += asf(p0.y << 16)         + asf(p1.y << 16);
        a.w += asf(p0.y & 0xFFFF0000u) + asf(p1.y & 0xFFFF0000u);
        reinterpret_cast<float4*>(out)[i] = a;
    } else {
        int j = i - MAIN4;               // < 65536
        float4 sum = make_float4(0.f, 0.f, 0.f, 0.f);
        #pragma unroll
        for (int q = 0; q < 15; ++q) {
            u32x2 v = *reinterpret_cast<const u32x2*>(
                gatep + (size_t)q * (E * 64) + (size_t)j * 4);
            sum.x += asf(v.x << 16);
            sum.y += asf(v.x & 0xFFFF0000u);
            sum.z += asf(v.y << 16);
            sum.w += asf(v.y & 0xFFFF0000u);
        }
        reinterpret_cast<float4*>(out + (size_t)E * M * D)[j] = sum;
    }
}

extern "C" void kernel_launch(void* const* d_in, const int* in_sizes, int n_in,
                              void* d_out, int out_size, void* d_ws, size_t ws_size,
                              hipStream_t stream)
{
    const float* x      = (const float*)d_in[0];
    const float* x_edge = (const float*)d_in[1];
    const float* W1     = (const float*)d_in[2];
    const float* b1     = (const float*)d_in[3];
    const float* W2     = (const float*)d_in[4];
    const float* b2     = (const float*)d_in[5];
    const float* W3     = (const float*)d_in[6];
    const float* b3     = (const float*)d_in[7];

    float* out = (float*)d_out;

    // ws: W3T 17,965,056 | h2t 1,056,768 | outp bf16 x2 12,582,912 | gatep bf16 x15 7,864,320
    char* ws = (char*)d_ws;
    unsigned short* w3t   = (unsigned short*)ws;
    unsigned short* h2t   = (unsigned short*)(ws + 17965056);
    unsigned short* outp  = (unsigned short*)(ws + 19021824);
    unsigned short* gatep = (unsigned short*)(ws + 31604736);

    mlp_kernel<<<E / 16, 256, 0, stream>>>(x_edge, W1, b1, W2, b2, h2t);
    w3t_kernel<<<dim3(129, NSLICE), 256, 0, stream>>>(W3, b3, w3t);
    gemm_kernel<<<816, 256, 0, stream>>>(x, h2t, w3t, out, outp, gatep);
    reduce_kernel<<<3328, 256, 0, stream>>>(out, outp, gatep);
}

// Round 16
// 135.788 us; speedup vs baseline: 4.2387x; 1.0170x over previous
//
#include <hip/hip_runtime.h>
#include <hip/hip_bf16.h>

#define E 4096
#define M 12
#define C 64
#define D 64
#define M0 5
#define XD 64
#define EC 128
#define MAIN (M*C*D)        // 49152
#define EXTRA (M0*C*XD)     // 20480
#define TOTAL (MAIN+EXTRA)  // 69632 = 17*4096
#define NSLICE 17
#define KDIM 8256           // per-slice K = 129*64
#define NKB 43              // uniform k-rows per block (129 = 3*43)

typedef float  f32x4  __attribute__((ext_vector_type(4)));
typedef __bf16 bf16x8 __attribute__((ext_vector_type(8)));
typedef unsigned int u32x4 __attribute__((ext_vector_type(4)));
typedef unsigned int u32x2 __attribute__((ext_vector_type(2)));

typedef const __attribute__((address_space(1))) void gvoid;
typedef __attribute__((address_space(3))) void lvoid;

__device__ __forceinline__ float silu_f(float v) { return v / (1.0f + __expf(-v)); }

__device__ __forceinline__ unsigned short f2bf(float f) {
    unsigned u = __builtin_bit_cast(unsigned, f);
    u += 0x7FFFu + ((u >> 16) & 1u);          // RNE
    return (unsigned short)(u >> 16);
}
__device__ __forceinline__ unsigned pack2(float a, float b) {
    return (unsigned)f2bf(a) | ((unsigned)f2bf(b) << 16);
}
__device__ __forceinline__ float asf(unsigned u) { return __builtin_bit_cast(float, u); }

// ---------- Kernel 1: MLP -> h2^T bf16 [129][E] (row 128 = ones) ----------
__global__ __launch_bounds__(256) void mlp_kernel(
    const float* __restrict__ x_edge, const float* __restrict__ W1,
    const float* __restrict__ b1, const float* __restrict__ W2,
    const float* __restrict__ b2, unsigned short* __restrict__ h2t)
{
    __shared__ float xe[16][128];
    __shared__ float h1s[16][128];
    const int t  = threadIdx.x;
    const int b0 = blockIdx.x * 16;
    const int j  = t & 127;
    const int rh = t >> 7;

    #pragma unroll
    for (int i = 0; i < 8; ++i) {
        int lin = t + i * 256;
        int r = lin >> 7, k = lin & 127;
        xe[r][k] = x_edge[(size_t)(b0 + r) * EC + k];
    }
    __syncthreads();
    {
        float acc[8];
        float bb = b1[j];
        #pragma unroll
        for (int it = 0; it < 8; ++it) acc[it] = bb;
        for (int k = 0; k < 128; ++k) {
            float w = W1[k * EC + j];
            #pragma unroll
            for (int it = 0; it < 8; ++it) acc[it] += xe[rh + it * 2][k] * w;
        }
        #pragma unroll
        for (int it = 0; it < 8; ++it) h1s[rh + it * 2][j] = silu_f(acc[it]);
    }
    __syncthreads();
    {
        float acc[8];
        float bb = b2[j];
        #pragma unroll
        for (int it = 0; it < 8; ++it) acc[it] = bb;
        for (int k = 0; k < 128; ++k) {
            float w = W2[k * EC + j];
            #pragma unroll
            for (int it = 0; it < 8; ++it) acc[it] += h1s[rh + it * 2][k] * w;
        }
        #pragma unroll
        for (int it = 0; it < 8; ++it)
            h2t[(size_t)j * E + (b0 + rh + it * 2)] = f2bf(silu_f(acc[it]));
    }
    if (t < 16) h2t[(size_t)128 * E + b0 + t] = 0x3F80;   // 1.0 bf16
}

// ---------- Kernel 2: W3T[s*64+d][k*64+c] = bf16(W3[k][s*4096+c*64+d]) ----------
__global__ __launch_bounds__(256) void w3t_kernel(
    const float* __restrict__ W3, const float* __restrict__ b3,
    unsigned short* __restrict__ w3t)
{
    const int k = blockIdx.x;   // 0..128
    const int s = blockIdx.y;   // 0..16
    __shared__ float tile[64][68];
    const int t = threadIdx.x;
    const float* src = ((k < 128) ? (W3 + (size_t)k * TOTAL) : b3) + s * 4096;

    const int c  = t >> 2;
    const int dp = (t & 3) * 16;
    #pragma unroll
    for (int i = 0; i < 4; ++i) {
        float4 v = *reinterpret_cast<const float4*>(src + c * 64 + dp + i * 4);
        *reinterpret_cast<float4*>(&tile[c][dp + i * 4]) = v;
    }
    __syncthreads();

    const int d  = t >> 2;
    const int cp = (t & 3) * 16;
    unsigned u[8];
    #pragma unroll
    for (int i = 0; i < 8; ++i)
        u[i] = pack2(tile[cp + 2 * i][d], tile[cp + 2 * i + 1][d]);
    unsigned short* dst = w3t + (size_t)(s * 64 + d) * KDIM + k * 64 + cp;
    *reinterpret_cast<u32x4*>(dst)     = u32x4{u[0], u[1], u[2], u[3]};
    *reinterpret_cast<u32x4*>(dst + 8) = u32x4{u[4], u[5], u[6], u[7]};
}

// ---------- Kernel 3: fused weight-gen + contraction ----------
// 816 blocks x 512 THREADS (8 waves, rf=2 each: 32 b-rows/wave, 256/block).
// Same block geometry/B-traffic as R12; per-wave regs ~<128 -> 4 waves/SIMD
// (2x the TLP of all prior rounds: the untested occupancy-quantum lever).
// Ring-3 LDS B (1 gload_lds/thread/k-row, counted vmcnt(1)); ASCALE + pure-
// MFMA KBODY (R12 numerics byte-identical).
__global__ __launch_bounds__(512, 4) void gemm_kernel(
    const float* __restrict__ x, const unsigned short* __restrict__ h2t,
    const unsigned short* __restrict__ w3t, float* __restrict__ out,
    unsigned short* __restrict__ outp, unsigned short* __restrict__ gatep)
{
    __shared__ __align__(16) unsigned short h2s[NKB * 256];   // 22016 B
    __shared__ __align__(16) unsigned short Bs[3][4096];      // 3 x 8 KB ring

    const int t  = threadIdx.x;       // 0..511
    const int w  = t >> 6;            // 0..7
    const int l  = t & 63;
    const int p  = l >> 4;
    const int lr = l & 15;

    // block decode, XCD-chunked (816 = 8*102, bijective)
    const int bid  = blockIdx.x;
    const int slot = (bid & 7) * 102 + (bid >> 3);
    const int grp  = slot >> 4;          // 0..50
    const int bx   = slot & 15;
    const int s    = grp / 3;            // 0..16
    const int kz   = grp % 3;
    const int k0   = kz * NKB;
    const int b0   = bx * 256;
    const int m    = (s < 12) ? s : (s - 12);

    // stage h2^T tile [43][256 cols] (512 B per row)
    {
        const char* h2g = (const char*)(h2t + (size_t)k0 * E + b0);
        for (int lin = t * 16; lin < NKB * 512; lin += 8192) {
            int kl = lin >> 9, off = lin & 511;
            *reinterpret_cast<u32x4*>((char*)h2s + lin) =
                *reinterpret_cast<const u32x4*>(h2g + (size_t)kl * (E * 2) + off);
        }
    }

    // A fragments: wave w owns b-rows [b0+w*32, b0+w*32+32), rf=2
    u32x4 xa[2][2];
    #pragma unroll
    for (int rf = 0; rf < 2; ++rf)
        #pragma unroll
        for (int s2 = 0; s2 < 2; ++s2) {
            const float* xp = x + (size_t)(b0 + w * 32 + rf * 16 + lr) * (M * C)
                              + m * 64 + s2 * 32 + p * 8;
            float4 a = *reinterpret_cast<const float4*>(xp);
            float4 b = *reinterpret_cast<const float4*>(xp + 4);
            xa[rf][s2] = u32x4{pack2(a.x, a.y), pack2(a.z, a.w),
                               pack2(b.x, b.y), pack2(b.z, b.w)};
        }

    // staging: wave w stages subtile j=w (cf=w>>1, s2=w&1); lane l -> 16B slot l
    const unsigned short* gsrc = w3t
        + (size_t)(s * 64 + (w >> 1) * 16 + lr) * KDIM
        + (size_t)k0 * 64 + ((w & 1) * 4 + p) * 8;

#define STAGE(buf, kr)                                                          \
    __builtin_amdgcn_global_load_lds(                                           \
        (gvoid*)(gsrc + (size_t)(kr) * 64),                                     \
        (lvoid*)(&Bs[buf][w * 512]), 16, 0, 0);

    f32x4 acc[2][4];
    #pragma unroll
    for (int a = 0; a < 2; ++a)
        #pragma unroll
        for (int b = 0; b < 4; ++b) acc[a][b] = f32x4{0.f, 0.f, 0.f, 0.f};

    u32x4 axs[2][2];   // h-scaled A fragments for the current k-row

// ASCALE: axs = bf16(h[b,kr] * x[b,c]) — pure VGPR VALU; lane's b-row = lr.
#define ASCALE(kr)                                                              \
    {                                                                           \
        _Pragma("unroll")                                                       \
        for (int rf = 0; rf < 2; ++rf) {                                        \
            unsigned hu = (unsigned)h2s[(kr) * 256 + w * 32 + rf * 16 + lr];    \
            float hf = asf(hu << 16);                                           \
            _Pragma("unroll")                                                   \
            for (int s2 = 0; s2 < 2; ++s2)                                      \
                _Pragma("unroll")                                               \
                for (int i = 0; i < 4; ++i) {                                   \
                    unsigned u = xa[rf][s2][i];                                 \
                    float lo = asf(u << 16) * hf;                               \
                    float hi = asf(u & 0xFFFF0000u) * hf;                       \
                    unsigned r;                                                 \
                    asm("v_cvt_pk_bf16_f32 %0, %1, %2"                          \
                        : "=v"(r) : "v"(lo), "v"(hi));                          \
                    axs[rf][s2][i] = r;                                         \
                }                                                               \
        }                                                                       \
    }

// KBODY: pure MFMA cluster, accumulating natively into acc (AGPR-only).
#define KBODY(curv)                                                             \
    {                                                                           \
        __builtin_amdgcn_s_setprio(1);                                          \
        _Pragma("unroll")                                                       \
        for (int cf = 0; cf < 4; ++cf) {                                        \
            u32x4 B0 = *reinterpret_cast<const u32x4*>(                         \
                &Bs[curv][(cf * 2 + 0) * 512 + l * 8]);                         \
            u32x4 B1 = *reinterpret_cast<const u32x4*>(                         \
                &Bs[curv][(cf * 2 + 1) * 512 + l * 8]);                         \
            _Pragma("unroll")                                                   \
            for (int rf = 0; rf < 2; ++rf) {                                    \
                acc[rf][cf] = __builtin_amdgcn_mfma_f32_16x16x32_bf16(          \
                    __builtin_bit_cast(bf16x8, axs[rf][0]),                     \
                    __builtin_bit_cast(bf16x8, B0), acc[rf][cf], 0, 0, 0);      \
                acc[rf][cf] = __builtin_amdgcn_mfma_f32_16x16x32_bf16(          \
                    __builtin_bit_cast(bf16x8, axs[rf][1]),                     \
                    __builtin_bit_cast(bf16x8, B1), acc[rf][cf], 0, 0, 0);      \
            }                                                                   \
        }                                                                       \
        __builtin_amdgcn_s_setprio(0);                                          \
    }

    __syncthreads();            // h2s visible; everything drained

    STAGE(0, 0);                // ring prologue: slots 0,1 in flight (1 ld each)
    STAGE(1, 1);

    int cur = 0;                // slot holding kr's data
    #pragma unroll 1
    for (int kr = 0; kr < NKB - 2; ++kr) {      // kr = 0..40
        // own kr-load landed (2 outstanding -> wait 1); own kr-1 LDS reads
        // retired (lgkm 0); barrier globalizes both facts.
        asm volatile("s_waitcnt vmcnt(1) lgkmcnt(0)" ::: "memory");
        __builtin_amdgcn_s_barrier();
        int nxt = (cur == 0) ? 2 : cur - 1;     // slot (kr+2)%3 == (kr-1)%3
        STAGE(nxt, kr + 2);                     // stage ASAP: ~2 iters lead time
        ASCALE(kr);                             // VALU; overlaps others' MFMA
        KBODY(cur);                             // pure MFMA burst
        cur = (cur == 2) ? 0 : cur + 1;
    }
    // kr = 41: 42's load may be outstanding (1)
    asm volatile("s_waitcnt vmcnt(1) lgkmcnt(0)" ::: "memory");
    __builtin_amdgcn_s_barrier();
    ASCALE(NKB - 2);
    KBODY(cur);
    cur = (cur == 2) ? 0 : cur + 1;
    // kr = 42: drain
    asm volatile("s_waitcnt vmcnt(0) lgkmcnt(0)" ::: "memory");
    __builtin_amdgcn_s_barrier();
    ASCALE(NKB - 1);
    KBODY(cur);
#undef STAGE
#undef ASCALE
#undef KBODY

    // epilogue: partial stores (no atomics)
    if (s < 12) {
        if (kz == 0) {
            #pragma unroll
            for (int rf = 0; rf < 2; ++rf)
                #pragma unroll
                for (int cf = 0; cf < 4; ++cf)
                    #pragma unroll
                    for (int r = 0; r < 4; ++r) {
                        int b = b0 + w * 32 + rf * 16 + p * 4 + r;
                        int d = cf * 16 + lr;
                        out[(size_t)b * (M * D) + s * D + d] = acc[rf][cf][r];
                    }
        } else {
            unsigned short* ob = outp + (size_t)(kz - 1) * (E * M * D);
            #pragma unroll
            for (int rf = 0; rf < 2; ++rf)
                #pragma unroll
                for (int cf = 0; cf < 4; ++cf)
                    #pragma unroll
                    for (int r = 0; r < 4; ++r) {
                        int b = b0 + w * 32 + rf * 16 + p * 4 + r;
                        int d = cf * 16 + lr;
                        ob[(size_t)b * (M * D) + s * D + d] = f2bf(acc[rf][cf][r]);
                    }
        }
    } else {
        unsigned short* gp = gatep + (size_t)((s - 12) * 3 + kz) * (E * 64);
        #pragma unroll
        for (int rf = 0; rf < 2; ++rf)
            #pragma unroll
            for (int cf = 0; cf < 4; ++cf)
                #pragma unroll
                for (int r = 0; r < 4; ++r) {
                    int b = b0 + w * 32 + rf * 16 + p * 4 + r;
                    int d = cf * 16 + lr;
                    gp[(size_t)b * 64 + d] = f2bf(acc[rf][cf][r]);
                }
    }
}

// ---------- Kernel 4: out += 2 bf16 main partials; gate = sum of 15 bf16 partials ----------
__global__ __launch_bounds__(256) void reduce_kernel(
    float* __restrict__ out, const unsigned short* __restrict__ outp,
    const unsigned short* __restrict__ gatep)
{
    const int MAIN4 = E * M * D / 4;     // 786432
    int i = blockIdx.x * 256 + threadIdx.x;
    if (i < MAIN4) {
        float4 a = reinterpret_cast<float4*>(out)[i];
        u32x2 p0 = *reinterpret_cast<const u32x2*>(outp + (size_t)i * 4);
        u32x2 p1 = *reinterpret_cast<const u32x2*>(outp + (size_t)E * M * D + (size_t)i * 4);
        a.x += asf(p0.x << 16)         + asf(p1.x << 16);
        a.y += asf(p0.x & 0xFFFF0000u) + asf(p1.x & 0xFFFF0000u);
        a.z += asf(p0.y << 16)         + asf(p1.y << 16);
        a.w += asf(p0.y & 0xFFFF0000u) + asf(p1.y & 0xFFFF0000u);
        reinterpret_cast<float4*>(out)[i] = a;
    } else {
        int j = i - MAIN4;               // < 65536
        float4 sum = make_float4(0.f, 0.f, 0.f, 0.f);
        #pragma unroll
        for (int q = 0; q < 15; ++q) {
            u32x2 v = *reinterpret_cast<const u32x2*>(
                gatep + (size_t)q * (E * 64) + (size_t)j * 4);
            sum.x += asf(v.x << 16);
            sum.y += asf(v.x & 0xFFFF0000u);
            sum.z += asf(v.y << 16);
            sum.w += asf(v.y & 0xFFFF0000u);
        }
        reinterpret_cast<float4*>(out + (size_t)E * M * D)[j] = sum;
    }
}

extern "C" void kernel_launch(void* const* d_in, const int* in_sizes, int n_in,
                              void* d_out, int out_size, void* d_ws, size_t ws_size,
                              hipStream_t stream)
{
    const float* x      = (const float*)d_in[0];
    const float* x_edge = (const float*)d_in[1];
    const float* W1     = (const float*)d_in[2];
    const float* b1     = (const float*)d_in[3];
    const float* W2     = (const float*)d_in[4];
    const float* b2     = (const float*)d_in[5];
    const float* W3     = (const float*)d_in[6];
    const float* b3     = (const float*)d_in[7];

    float* out = (float*)d_out;

    // ws: W3T 17,965,056 | h2t 1,056,768 | outp bf16 x2 12,582,912 | gatep bf16 x15 7,864,320
    char* ws = (char*)d_ws;
    unsigned short* w3t   = (unsigned short*)ws;
    unsigned short* h2t   = (unsigned short*)(ws + 17965056);
    unsigned short* outp  = (unsigned short*)(ws + 19021824);
    unsigned short* gatep = (unsigned short*)(ws + 31604736);

    mlp_kernel<<<E / 16, 256, 0, stream>>>(x_edge, W1, b1, W2, b2, h2t);
    w3t_kernel<<<dim3(129, NSLICE), 256, 0, stream>>>(W3, b3, w3t);
    gemm_kernel<<<816, 512, 0, stream>>>(x, h2t, w3t, out, outp, gatep);
    reduce_kernel<<<3328, 256, 0, stream>>>(out, outp, gatep);
}